// Round 10
// baseline (1400.543 us; speedup 1.0000x reference)
//
#include <hip/hip_runtime.h>
#include <math.h>

#define NTH 256
#define SB 7   // samples per block: 63 live h-rows of 64 (4 waves x 16)

typedef __attribute__((ext_vector_type(8))) short bf16x8;
typedef __attribute__((ext_vector_type(4))) float f32x4;
typedef __attribute__((ext_vector_type(2))) unsigned short us2;
typedef __attribute__((ext_vector_type(4))) unsigned short us4;

// R5/R6-proven fast activations (__expf = native v_mul+v_exp path; rcp ~1ulp).
__device__ __forceinline__ float fast_sigmoid(float x) {
    return __builtin_amdgcn_rcpf(1.0f + __expf(-x));
}
__device__ __forceinline__ float fast_tanh(float x) {
    return fmaf(-2.0f, __builtin_amdgcn_rcpf(__expf(2.0f * x) + 1.0f), 1.0f);
}
__device__ __forceinline__ short f2bf(float x) {
    unsigned u = __float_as_uint(x);
    return (short)((u + 0x7FFFu + ((u >> 16) & 1u)) >> 16);   // RNE
}
// HW packed f32->bf16 (RNE, matches f2bf) — proven in passing R7/R9.
__device__ __forceinline__ unsigned pk_bf16(float lo, float hi) {
    unsigned r;
    asm("v_cvt_pk_bf16_f32 %0, %1, %2" : "=v"(r) : "v"(lo), "v"(hi));
    return r;
}
__device__ __forceinline__ float bf2f(unsigned short u) {
    return __uint_as_float(((unsigned)u) << 16);   // exact widening
}

// LDS map (dwords), total 7470 dw = 29,880 B -> 30,208 B alloc ->
// 4 blocks/CU under the 128 KiB effective cap (R4-R9 evidence).
//  sUb  @0     (3780) [63 rows][120] bf16 u-plane; D aliases sT1 (fp32) here
//  SCR  @3780  (3240) A: S0 fp32(1080)+S1b/S2b/S3b bf16(540 ea)+SY fp32 over S1b/S2b
//                     B: Vb bf16(1080)+Y fp32(2160) | C: sH0b/sH1b bf16 [64][48]
//                     D: sTF(945)
//  AUX  @7020  (90)   A: sKV/sKS | B: sMU/sRS | D: sST
//  W    @7110  (360)  A: wq2..ln2b | B overlay: bo4/ln4g/ln4b
extern "C" __global__ void __launch_bounds__(NTH, 3)
se_kernel(const float* __restrict__ x,
          const float* __restrict__ bn_g, const float* __restrict__ bn_b,
          const float* __restrict__ bn_m, const float* __restrict__ bn_v,
          const float* __restrict__ wq2, const float* __restrict__ wk2,
          const float* __restrict__ wv2, const float* __restrict__ wo2,
          const float* __restrict__ bo2, const float* __restrict__ ln2g,
          const float* __restrict__ ln2b,
          const float* __restrict__ wq4, const float* __restrict__ wk4,
          const float* __restrict__ wv4, const float* __restrict__ wo4,
          const float* __restrict__ bo4, const float* __restrict__ ln4g,
          const float* __restrict__ ln4b,
          const float* __restrict__ w_ih, const float* __restrict__ w_hh,
          const float* __restrict__ b_ih, const float* __restrict__ b_hh,
          const float* __restrict__ cg_w, const float* __restrict__ cg_uw,
          const float* __restrict__ cg_ub,
          const float* __restrict__ w6, const float* __restrict__ b6,
          const float* __restrict__ w7, const float* __restrict__ b7,
          const float* __restrict__ rev_w, const float* __restrict__ rev_b,
          float* __restrict__ out, int Bn)
{
    __shared__ __align__(16) float sm[7470];
    const int tid  = threadIdx.x;
    const int lane = tid & 63;
    const int wv   = tid >> 6;
    const int b0   = blockIdx.x * SB;
    const int nsamp = min(SB, Bn - b0);

    unsigned short* sUb = (unsigned short*)sm;   // 63x120 bf16 (3780 dw)
    float* SCR = sm + 3780;                      // 3240 dw
    // Phase-A scratch:
    float* S0 = SCR;                                   // 1080 fp32 (BN-x, then o)
    unsigned short* S1b = (unsigned short*)(SCR + 1080);   // 1080 bf16 (Q)
    unsigned short* S2b = (unsigned short*)(SCR + 1620);   // 1080 bf16 (K)
    unsigned short* S3b = (unsigned short*)(SCR + 2160);   // 1080 bf16 (V)
    float* SY = SCR + 1080;                            // 1080 fp32 y (over dead Q/K)
    // Phase-B scratch:
    unsigned short* Vb = (unsigned short*)SCR;         // [2][1080] bf16 (1080 dw)
    float* Y0 = SCR + 1080;                            // [2][1080] fp32 (2160 dw)
    // Phase-C planes (bf16, pitch 48 for 16B-aligned rows):
    unsigned short* sH0b = (unsigned short*)SCR;           // 64x48 (1536 dw)
    unsigned short* sH1b = (unsigned short*)(SCR + 1536);  // 64x48 (1536 dw)
    // AUX (phase-exclusive):
    float* sKV = sm + 7020; float* sKS = sm + 7101;    // A
    float* sMU = sm + 7020; float* sRS = sm + 7038;    // B
    float* sST = sm + 7056;                            // D
    // W region: A weights, overlaid by B params after A completes.
    float* sWQ2 = sm + 7110; float* sWK2 = sm + 7191;
    float* sWV2 = sm + 7272; float* sWO2 = sm + 7353;
    float* sBO2 = sm + 7434; float* sLN2G = sm + 7443; float* sLN2B = sm + 7452;
    float* sBO4 = sm + 7110; float* sLN4G = sm + 7230; float* sLN4B = sm + 7350;
    // Phase-D scratch:
    float* sT1 = sm;             // 3780 fp32 (aliases sUb; dead in D)
    float* sTF = SCR;            // 945 (aliases dead sH0b after conv6)

    // ---- Phase 0: stage Phase-A weights ----
    for (int i = tid; i < 81; i += NTH) {
        sWQ2[i] = wq2[i]; sWK2[i] = wk2[i]; sWV2[i] = wv2[i]; sWO2[i] = wo2[i];
    }
    if (tid < 9) { sBO2[tid] = bo2[tid]; sLN2G[tid] = ln2g[tid]; sLN2B[tid] = ln2b[tid]; }
    __syncthreads();

    // ---- Phase A: lin_attn_2 per sample -> u rows (bf16) in sUb.
    //      Q/K/V staged as bf16 (adds <=2^-9 input rounding, same order as
    //      the u-quantization already proven harmless in R9).
    for (int ss = 0; ss < SB; ++ss) {
        if (ss < nsamp) {
            const int b = b0 + ss;
            for (int i = tid; i < 1080; i += NTH) {
                float xv = x[(size_t)b * 1080 + i];
                S0[i] = (xv - bn_m[i]) * rsqrtf(bn_v[i] + 1e-5f) * bn_g[i] + bn_b[i];
            }
            __syncthreads();
            for (int idx = tid; idx < 1080; idx += NTH) {
                int s = idx / 9, e = idx - s * 9;
                float aq = 0.f, ak = 0.f, av = 0.f;
                #pragma unroll
                for (int d = 0; d < 9; ++d) {
                    float xv = S0[s * 9 + d];
                    aq = fmaf(xv, sWQ2[e * 9 + d], aq);
                    ak = fmaf(xv, sWK2[e * 9 + d], ak);
                    av = fmaf(xv, sWV2[e * 9 + d], av);
                }
                S1b[idx] = (unsigned short)f2bf(aq >= 0.f ? aq + 1.f : __expf(aq));
                S2b[idx] = (unsigned short)f2bf(ak >= 0.f ? ak + 1.f : __expf(ak));
                S3b[idx] = (unsigned short)f2bf(av);
            }
            __syncthreads();
            if (tid < 81) {
                int d = tid / 9, e = tid - d * 9;
                float acc = 0.f;
                for (int s = 0; s < 120; ++s)
                    acc = fmaf(bf2f(S2b[s * 9 + d]), bf2f(S3b[s * 9 + e]), acc);
                sKV[tid] = acc;
            } else if (tid < 90) {
                int d = tid - 81;
                float acc = 0.f;
                for (int s = 0; s < 120; ++s) acc += bf2f(S2b[s * 9 + d]);
                sKS[d] = acc;
            }
            __syncthreads();
            for (int idx = tid; idx < 1080; idx += NTH) {
                int s = idx / 9, e = idx - s * 9;
                float num = 0.f, den = 0.f;
                #pragma unroll
                for (int d = 0; d < 9; ++d) {
                    float qv = bf2f(S1b[s * 9 + d]);
                    num = fmaf(qv, sKV[d * 9 + e], num);
                    den = fmaf(qv, sKS[d], den);
                }
                S0[idx] = num / fmaxf(den, 1e-6f);
            }
            __syncthreads();
            for (int idx = tid; idx < 1080; idx += NTH) {   // y over dead Q/K
                int s = idx / 9, f = idx - s * 9;
                float acc = sBO2[f] + S0[s * 9 + f];
                #pragma unroll
                for (int e = 0; e < 9; ++e) acc = fmaf(S0[s * 9 + e], sWO2[f * 9 + e], acc);
                SY[idx] = acc;
            }
            __syncthreads();
            if (tid < 120) {
                int s = tid;
                float sum = 0.f, sq = 0.f;
                #pragma unroll
                for (int f = 0; f < 9; ++f) { float v = SY[s * 9 + f]; sum += v; sq = fmaf(v, v, sq); }
                float mu = sum * (1.f / 9.f);
                float rs = rsqrtf(sq * (1.f / 9.f) - mu * mu + 1e-5f);
                #pragma unroll
                for (int f = 0; f < 9; ++f) {
                    float uo = (SY[s * 9 + f] - mu) * rs * sLN2G[f] + sLN2B[f];
                    sUb[(ss * 9 + f) * 120 + s] = (unsigned short)f2bf(uo);
                }
            }
        }
        __syncthreads();
    }

    // ---- Phase B: lin_attn_4, o == V (R4-proven delete). V staged bf16. ----
    for (int i = tid; i < 120; i += NTH) { sBO4[i] = bo4[i]; sLN4G[i] = ln4g[i]; sLN4B[i] = ln4b[i]; }
    for (int p = 0; p < 4; ++p) {
        const int sp = tid / 120, erow = tid - sp * 120;
        const int smp = p * 2 + sp;
        const bool act = (tid < 240) && (smp < SB);
        if (act) {   // V row erow for all 9 vars of sample smp (bf16 u reads)
            const unsigned short* uBb = sUb + smp * 1080;
            float acc[9];
            #pragma unroll
            for (int v = 0; v < 9; ++v) acc[v] = 0.f;
            const float* w0p = &wv4[erow * 120];
            for (int dq = 0; dq < 30; ++dq) {
                float4 wA = *(const float4*)&w0p[dq * 4];
                #pragma unroll
                for (int v = 0; v < 9; ++v) {
                    us4 ub = *(const us4*)&uBb[v * 120 + dq * 4];
                    acc[v] = fmaf(wA.x, bf2f(ub[0]), acc[v]);
                    acc[v] = fmaf(wA.y, bf2f(ub[1]), acc[v]);
                    acc[v] = fmaf(wA.z, bf2f(ub[2]), acc[v]);
                    acc[v] = fmaf(wA.w, bf2f(ub[3]), acc[v]);
                }
            }
            unsigned short* dst = Vb + sp * 1080;
            #pragma unroll
            for (int v = 0; v < 9; ++v) dst[v * 120 + erow] = (unsigned short)f2bf(acc[v]);
        }
        __syncthreads();
        if (act) {   // Y row erow (wo4 pass + residual; bf16 V reads)
            const unsigned short* vBb = Vb + sp * 1080;
            float acc[9];
            #pragma unroll
            for (int v = 0; v < 9; ++v) acc[v] = 0.f;
            const float* w0p = &wo4[erow * 120];
            for (int dq = 0; dq < 30; ++dq) {
                float4 wA = *(const float4*)&w0p[dq * 4];
                #pragma unroll
                for (int v = 0; v < 9; ++v) {
                    us4 ub = *(const us4*)&vBb[v * 120 + dq * 4];
                    acc[v] = fmaf(wA.x, bf2f(ub[0]), acc[v]);
                    acc[v] = fmaf(wA.y, bf2f(ub[1]), acc[v]);
                    acc[v] = fmaf(wA.z, bf2f(ub[2]), acc[v]);
                    acc[v] = fmaf(wA.w, bf2f(ub[3]), acc[v]);
                }
            }
            float* Y = Y0 + sp * 1080;
            #pragma unroll
            for (int v = 0; v < 9; ++v)
                Y[v * 120 + erow] = acc[v] + sBO4[erow] + bf2f(vBb[v * 120 + erow]);
        }
        __syncthreads();
        if (tid < 18 && (p * 2 + tid / 9) < SB) {   // LN stats (fp32 Y)
            int sp2 = tid / 9, v = tid - sp2 * 9;
            const float* Y = Y0 + sp2 * 1080 + v * 120;
            float sum = 0.f, sq = 0.f;
            for (int e = 0; e < 120; ++e) { float t = Y[e]; sum += t; sq = fmaf(t, t, sq); }
            float mu = sum * (1.f / 120.f);
            sMU[tid] = mu;
            sRS[tid] = rsqrtf(sq * (1.f / 120.f) - mu * mu + 1e-5f);
        }
        __syncthreads();
        for (int idx = tid; idx < 540; idx += NTH) {   // LN apply -> bf16 sUb
            int sp2 = idx / 270, off = idx - sp2 * 270;
            int smp2 = p * 2 + sp2;
            int v = off / 30, qq = off - v * 30;
            if (smp2 < SB) {
                const float* Y = Y0 + sp2 * 1080;
                float4 y = *(const float4*)&Y[v * 120 + qq * 4];
                float4 g = *(const float4*)&sLN4G[qq * 4];
                float4 bb = *(const float4*)&sLN4B[qq * 4];
                float mu = sMU[sp2 * 9 + v], rs = sRS[sp2 * 9 + v];
                float ox = (y.x - mu) * rs * g.x + bb.x;
                float oy = (y.y - mu) * rs * g.y + bb.y;
                float oz = (y.z - mu) * rs * g.z + bb.z;
                float ow = (y.w - mu) * rs * g.w + bb.w;
                uint2 pk; pk.x = pk_bf16(ox, oy); pk.y = pk_bf16(oz, ow);
                *(uint2*)&sUb[(smp2 * 9 + v) * 120 + qq * 4] = pk;
            }
        }
        __syncthreads();
    }

    // ---- Phase C: CGLSTM via MFMA — bf16 h planes (pitch 48), barrier-free.
    //      The A-fragment IS the 8 bf16 the lane reads: one ds_read_b128,
    //      zero conversion. Recurrence numerics identical to R9 (h was
    //      bf16-quantized for MFMA anyway); only out0/conv6 gain <=2^-9.
    for (int i = tid; i < 1536; i += NTH) ((float*)sH0b)[i] = 0.f;   // h0 = 0
    __syncthreads();

    const int c = lane & 15, q = lane >> 4;
    bf16x8 bfr[8]; float wxv[8], bsv[8];
    int grow[4]; int pcol;
    {
        // Probe 1: A(m,0)=m, B(0,n)=1  -> D slot value = its ROW
        // Probe 2: A(m,0)=1, B(0,n)=n  -> D slot value = its COLUMN
        bf16x8 pa, pb, pa2, pb2;
        #pragma unroll
        for (int j = 0; j < 8; ++j) { pa[j] = 0; pb[j] = 0; pa2[j] = 0; pb2[j] = 0; }
        if (q == 0) {
            pa[0]  = f2bf((float)c); pb[0]  = f2bf(1.0f);
            pa2[0] = f2bf(1.0f);     pb2[0] = f2bf((float)c);
        }
        f32x4 zc; zc[0] = zc[1] = zc[2] = zc[3] = 0.f;
        f32x4 prr = __builtin_amdgcn_mfma_f32_16x16x32_bf16(pa,  pb,  zc, 0, 0, 0);
        f32x4 pcc = __builtin_amdgcn_mfma_f32_16x16x32_bf16(pa2, pb2, zc, 0, 0, 0);
        #pragma unroll
        for (int r = 0; r < 4; ++r) grow[r] = wv * 16 + (int)(prr[r] + 0.5f);
        pcol = (int)(pcc[0] + 0.5f);

        #pragma unroll
        for (int T = 0; T < 8; ++T) {
            int gate = T >> 1, kk = ((T & 1) << 4) + pcol;
            const float* wr; float wx, bs;
            if (gate < 3) {
                int n = gate * 32 + kk;
                wr = &w_hh[n * 32]; wx = w_ih[n]; bs = b_ih[n] + b_hh[n];
            } else {
                wr = &cg_uw[kk * 32]; wx = cg_w[kk]; bs = cg_ub[kk];
            }
            bf16x8 tv;
            #pragma unroll
            for (int j = 0; j < 8; ++j) tv[j] = f2bf(wr[q * 8 + j]);
            bfr[T] = tv; wxv[T] = wx; bsv[T] = bs;
        }
    }
    float cst[8];
    #pragma unroll
    for (int i = 0; i < 8; ++i) cst[i] = 0.f;
    const int live9 = nsamp * 9;
    const unsigned short* ar0 = &sH0b[(wv * 16 + c) * 48 + q * 8];
    const unsigned short* ar1 = &sH1b[(wv * 16 + c) * 48 + q * 8];

// One LSTM step, no barrier: read plane RP (b128 = ready bf16 fragment),
// write plane WPL (disjoint). h stored bf16: pk pairs (ho[r], ho[4+r]) ->
// cols pcol and pcol+16 of row grow[r].
#define LSTM_STEP(RP, WPL, XARR)                                               \
    {                                                                          \
        bf16x8 af = *(const bf16x8*)(RP);                                      \
        f32x4 acc[8];                                                          \
        _Pragma("unroll")                                                      \
        for (int T = 0; T < 8; ++T) {                                          \
            f32x4 ci;                                                          \
            _Pragma("unroll")                                                  \
            for (int r = 0; r < 4; ++r) ci[r] = fmaf(wxv[T], XARR[r], bsv[T]); \
            acc[T] = __builtin_amdgcn_mfma_f32_16x16x32_bf16(af, bfr[T], ci, 0, 0, 0); \
        }                                                                      \
        float ho[8];                                                           \
        _Pragma("unroll")                                                      \
        for (int kh = 0; kh < 2; ++kh) {                                       \
            _Pragma("unroll")                                                  \
            for (int r = 0; r < 4; ++r) {                                      \
                float si  = fast_sigmoid(acc[kh][r]);                          \
                float sf  = fast_sigmoid(acc[2 + kh][r]);                      \
                float tg  = fast_tanh(acc[4 + kh][r]);                         \
                float sgc = fast_sigmoid(acc[6 + kh][r]);                      \
                float cn = fmaf(sf, cst[kh * 4 + r], si * tg);                 \
                cst[kh * 4 + r] = cn;                                          \
                ho[kh * 4 + r] = sgc * fast_tanh(cn);                          \
            }                                                                  \
        }                                                                      \
        _Pragma("unroll")                                                      \
        for (int r = 0; r < 4; ++r) {                                          \
            unsigned u = pk_bf16(ho[r], ho[4 + r]);                            \
            (WPL)[grow[r] * 48 + pcol]      = (unsigned short)(u & 0xffffu);   \
            (WPL)[grow[r] * 48 + 16 + pcol] = (unsigned short)(u >> 16);       \
        }                                                                      \
    }

    for (int t = 0; t < 120; t += 2) {
        float xa[4], xb[4];
        #pragma unroll
        for (int r = 0; r < 4; ++r) {
            if (grow[r] < live9) {
                us2 xv = *(const us2*)&sUb[grow[r] * 120 + t];
                xa[r] = bf2f(xv[0]); xb[r] = bf2f(xv[1]);
            } else { xa[r] = 0.f; xb[r] = 0.f; }
        }
        LSTM_STEP(ar0, sH1b, xa)     // even step: plane0 -> plane1
        LSTM_STEP(ar1, sH0b, xb)     // odd step:  plane1 -> plane0
    }
    __syncthreads();   // publish final h (plane 0) to all waves

    // cglstm_out (output 0) from the bf16 h-plane (exact widening)
    for (int idx = tid; idx < SB * 288; idx += NTH) {
        int ssd = idx / 288, r = idx - ssd * 288;
        if (ssd < nsamp) {
            int v = r >> 5, k = r & 31;
            out[(size_t)(b0 + ssd) * 288 + r] = bf2f(sH0b[(ssd * 9 + v) * 48 + k]);
        }
    }

    // ---- Phase D: conv6(softplus) -> conv7(tanh) -> RevIN ----
    for (int idx = tid; idx < SB * 540; idx += NTH) {
        int ssd = idx / 540, rem = idx - ssd * 540;
        int v = rem / 60, j = rem - v * 60;
        if (ssd < nsamp) {
            float acc = b6[j];
            const float4* wr4 = (const float4*)&w6[j * 32];
            const unsigned short* hrow = &sH0b[(ssd * 9 + v) * 48];
            #pragma unroll
            for (int qq = 0; qq < 8; ++qq) {
                float4 w = wr4[qq];
                us4 hb = *(const us4*)&hrow[qq * 4];
                acc = fmaf(w.x, bf2f(hb[0]), acc); acc = fmaf(w.y, bf2f(hb[1]), acc);
                acc = fmaf(w.z, bf2f(hb[2]), acc); acc = fmaf(w.w, bf2f(hb[3]), acc);
            }
            sT1[idx] = acc > 15.f ? acc : log1pf(__expf(acc));
        }
    }
    __syncthreads();
    for (int idx = tid; idx < SB * 135; idx += NTH) {
        int ssd = idx / 135, rem = idx - ssd * 135;
        int v = rem / 15, f = rem - v * 15;
        if (ssd < nsamp) {
            float acc = b7[f];
            const float4* wr = (const float4*)&w7[f * 60];
            const float4* tv = (const float4*)&sT1[ssd * 540 + v * 60];
            #pragma unroll
            for (int qq = 0; qq < 15; ++qq) {
                float4 w = wr[qq], h = tv[qq];
                acc = fmaf(w.x, h.x, acc); acc = fmaf(w.y, h.y, acc);
                acc = fmaf(w.z, h.z, acc); acc = fmaf(w.w, h.w, acc);
            }
            sTF[idx] = fast_tanh(acc);
        }
    }
    __syncthreads();
    if (tid < SB && tid < nsamp) {
        const float* tf = &sTF[tid * 135];
        float sum = 0.f;
        for (int i = 0; i < 135; ++i) sum += tf[i];
        float mu = sum * (1.f / 135.f);
        float sq = 0.f;
        for (int i = 0; i < 135; ++i) { float d = tf[i] - mu; sq = fmaf(d, d, sq); }
        float sd = sqrtf(sq * (1.f / 134.f));  // ddof=1
        sST[tid * 2]     = mu;
        sST[tid * 2 + 1] = 1.f / fmaxf(sd, 1e-5f);
    }
    __syncthreads();
    const size_t encbase = (size_t)Bn * 288;
    for (int idx = tid; idx < SB * 135; idx += NTH) {
        int ssd = idx / 135, j = idx - ssd * 135;
        if (ssd < nsamp) {
            int qq = j / 15, pp = j - qq * 15;
            float val = (sTF[ssd * 135 + pp * 9 + qq] - sST[ssd * 2]) * sST[ssd * 2 + 1] * rev_w[j] + rev_b[j];
            out[encbase + (size_t)(b0 + ssd) * 135 + j] = val;
        }
    }
}

extern "C" void kernel_launch(void* const* d_in, const int* in_sizes, int n_in,
                              void* d_out, int out_size, void* d_ws, size_t ws_size,
                              hipStream_t stream) {
    const float* x    = (const float*)d_in[0];
    const float* bn_g = (const float*)d_in[1];
    const float* bn_b = (const float*)d_in[2];
    const float* bn_m = (const float*)d_in[3];
    const float* bn_v = (const float*)d_in[4];
    const float* wq2  = (const float*)d_in[5];
    const float* wk2  = (const float*)d_in[6];
    const float* wv2  = (const float*)d_in[7];
    const float* wo2  = (const float*)d_in[8];
    const float* bo2  = (const float*)d_in[9];
    const float* ln2g = (const float*)d_in[10];
    const float* ln2b = (const float*)d_in[11];
    const float* wq4  = (const float*)d_in[12];
    const float* wk4  = (const float*)d_in[13];
    const float* wv4  = (const float*)d_in[14];
    const float* wo4  = (const float*)d_in[15];
    const float* bo4  = (const float*)d_in[16];
    const float* ln4g = (const float*)d_in[17];
    const float* ln4b = (const float*)d_in[18];
    const float* w_ih = (const float*)d_in[19];
    const float* w_hh = (const float*)d_in[20];
    const float* b_ih = (const float*)d_in[21];
    const float* b_hh = (const float*)d_in[22];
    const float* cg_w = (const float*)d_in[23];
    const float* cg_uw= (const float*)d_in[24];
    const float* cg_ub= (const float*)d_in[25];
    const float* w6   = (const float*)d_in[26];
    const float* b6   = (const float*)d_in[27];
    const float* w7   = (const float*)d_in[28];
    const float* b7   = (const float*)d_in[29];
    const float* rev_w= (const float*)d_in[30];
    const float* rev_b= (const float*)d_in[31];

    int Bn = in_sizes[0] / 1080;
    int grid = (Bn + SB - 1) / SB;
    hipLaunchKernelGGL(se_kernel, dim3(grid), dim3(NTH), 0, stream,
                       x, bn_g, bn_b, bn_m, bn_v, wq2, wk2, wv2, wo2, bo2, ln2g, ln2b,
                       wq4, wk4, wv4, wo4, bo4, ln4g, ln4b,
                       w_ih, w_hh, b_ih, b_hh, cg_w, cg_uw, cg_ub,
                       w6, b6, w7, b7, rev_w, rev_b,
                       (float*)d_out, Bn);
}

// Round 13
// 1319.681 us; speedup vs baseline: 1.0613x; 1.0613x over previous
//
#include <hip/hip_runtime.h>
#include <math.h>

#define NTH 256
#define SB 7   // samples per block: 63 live h-rows of 64 (4 waves x 16)

typedef __attribute__((ext_vector_type(8))) short bf16x8;
typedef __attribute__((ext_vector_type(4))) float f32x4;
typedef __attribute__((ext_vector_type(2))) unsigned short us2;
typedef __attribute__((ext_vector_type(4))) unsigned short us4;

// R5/R6-proven fast activations (__expf = native v_mul+v_exp path; rcp ~1ulp).
// NOTE (R7/R8/R11/R12): every hand-lowered exp2 variant (libm exp2f, the
// builtin, bare asm, asm+s_nop) either regressed 19% or corrupted the
// recurrence. Only compiler-emitted __expf is trustworthy here.
__device__ __forceinline__ float fast_sigmoid(float x) {
    return __builtin_amdgcn_rcpf(1.0f + __expf(-x));
}
__device__ __forceinline__ float fast_tanh(float x) {
    return fmaf(-2.0f, __builtin_amdgcn_rcpf(__expf(2.0f * x) + 1.0f), 1.0f);
}
__device__ __forceinline__ short f2bf(float x) {
    unsigned u = __float_as_uint(x);
    return (short)((u + 0x7FFFu + ((u >> 16) & 1u)) >> 16);   // RNE
}
// HW packed f32->bf16 (RNE, matches f2bf) — proven in passing R7/R9.
__device__ __forceinline__ unsigned pk_bf16(float lo, float hi) {
    unsigned r;
    asm("v_cvt_pk_bf16_f32 %0, %1, %2" : "=v"(r) : "v"(lo), "v"(hi));
    return r;
}
__device__ __forceinline__ float bf2f(unsigned short u) {
    return __uint_as_float(((unsigned)u) << 16);   // exact widening
}

// LDS map (dwords), total 9862 dw = 39,448 B -> 3 blocks/CU (R9-proven).
//  sUb  @0     (3780) [63 rows][120] bf16 u-plane; Phase D aliases sT1 (fp32 3780)
//  SCR  @3780  (5632) A: S0..S3 | B: V[2]+Y[2] | C: sH0(2816)+sH1(2816) | D: sTF in sH1
//  AUX  @9412  (90)   A: sKV/sKS | B: sMU/sRS | D: sST
//  W    @9502  (360)  A: wq2..ln2b | B overlay: bo4/ln4g/ln4b (B runs after A)
extern "C" __global__ void __launch_bounds__(NTH, 3)
se_kernel(const float* __restrict__ x,
          const float* __restrict__ bn_g, const float* __restrict__ bn_b,
          const float* __restrict__ bn_m, const float* __restrict__ bn_v,
          const float* __restrict__ wq2, const float* __restrict__ wk2,
          const float* __restrict__ wv2, const float* __restrict__ wo2,
          const float* __restrict__ bo2, const float* __restrict__ ln2g,
          const float* __restrict__ ln2b,
          const float* __restrict__ wq4, const float* __restrict__ wk4,
          const float* __restrict__ wv4, const float* __restrict__ wo4,
          const float* __restrict__ bo4, const float* __restrict__ ln4g,
          const float* __restrict__ ln4b,
          const float* __restrict__ w_ih, const float* __restrict__ w_hh,
          const float* __restrict__ b_ih, const float* __restrict__ b_hh,
          const float* __restrict__ cg_w, const float* __restrict__ cg_uw,
          const float* __restrict__ cg_ub,
          const float* __restrict__ w6, const float* __restrict__ b6,
          const float* __restrict__ w7, const float* __restrict__ b7,
          const float* __restrict__ rev_w, const float* __restrict__ rev_b,
          float* __restrict__ out, int Bn)
{
    __shared__ __align__(16) float sm[9862];
    const int tid  = threadIdx.x;
    const int lane = tid & 63;
    const int wv   = tid >> 6;
    const int b0   = blockIdx.x * SB;
    const int nsamp = min(SB, Bn - b0);

    unsigned short* sUb = (unsigned short*)sm;   // 63x120 bf16 (3780 dw)
    float* SCR = sm + 3780;                      // 5632
    // AUX (phase-exclusive):
    float* sKV = sm + 9412; float* sKS = sm + 9493;   // A
    float* sMU = sm + 9412; float* sRS = sm + 9430;   // B
    float* sST = sm + 9448;                            // D
    // W region: A weights, overlaid by B params after A completes.
    float* sWQ2 = sm + 9502; float* sWK2 = sm + 9583;
    float* sWV2 = sm + 9664; float* sWO2 = sm + 9745;
    float* sBO2 = sm + 9826; float* sLN2G = sm + 9835; float* sLN2B = sm + 9844;
    float* sBO4 = sm + 9502; float* sLN4G = sm + 9622; float* sLN4B = sm + 9742;
    // Phase C planes / Phase D scratch:
    float* sH0 = SCR;            // 2816 (final h lands here)
    float* sH1 = SCR + 2816;     // 2816
    float* sT1 = sm;             // 3780 fp32 (aliases sUb; dead in D)
    float* sTF = SCR + 2816;     // 945 (aliases dead sH1)

    // ---- Phase 0: stage Phase-A weights ----
    for (int i = tid; i < 81; i += NTH) {
        sWQ2[i] = wq2[i]; sWK2[i] = wk2[i]; sWV2[i] = wv2[i]; sWO2[i] = wo2[i];
    }
    if (tid < 9) { sBO2[tid] = bo2[tid]; sLN2G[tid] = ln2g[tid]; sLN2B[tid] = ln2b[tid]; }
    __syncthreads();

    // ---- Phase A: lin_attn_2 per sample -> u rows (bf16) in sUb ----
    float* S0 = SCR; float* S1 = SCR + 1080; float* S2 = SCR + 2160; float* S3 = SCR + 3240;
    for (int ss = 0; ss < SB; ++ss) {
        if (ss < nsamp) {
            const int b = b0 + ss;
            for (int i = tid; i < 1080; i += NTH) {
                float xv = x[(size_t)b * 1080 + i];
                S0[i] = (xv - bn_m[i]) * rsqrtf(bn_v[i] + 1e-5f) * bn_g[i] + bn_b[i];
            }
            __syncthreads();
            for (int idx = tid; idx < 1080; idx += NTH) {
                int s = idx / 9, e = idx - s * 9;
                float aq = 0.f, ak = 0.f, av = 0.f;
                #pragma unroll
                for (int d = 0; d < 9; ++d) {
                    float xv = S0[s * 9 + d];
                    aq = fmaf(xv, sWQ2[e * 9 + d], aq);
                    ak = fmaf(xv, sWK2[e * 9 + d], ak);
                    av = fmaf(xv, sWV2[e * 9 + d], av);
                }
                S1[idx] = aq >= 0.f ? aq + 1.f : __expf(aq);
                S2[idx] = ak >= 0.f ? ak + 1.f : __expf(ak);
                S3[idx] = av;
            }
            __syncthreads();
            if (tid < 81) {
                int d = tid / 9, e = tid - d * 9;
                float acc = 0.f;
                for (int s = 0; s < 120; ++s) acc = fmaf(S2[s * 9 + d], S3[s * 9 + e], acc);
                sKV[tid] = acc;
            } else if (tid < 90) {
                int d = tid - 81;
                float acc = 0.f;
                for (int s = 0; s < 120; ++s) acc += S2[s * 9 + d];
                sKS[d] = acc;
            }
            __syncthreads();
            for (int idx = tid; idx < 1080; idx += NTH) {
                int s = idx / 9, e = idx - s * 9;
                float num = 0.f, den = 0.f;
                #pragma unroll
                for (int d = 0; d < 9; ++d) {
                    float qv = S1[s * 9 + d];
                    num = fmaf(qv, sKV[d * 9 + e], num);
                    den = fmaf(qv, sKS[d], den);
                }
                S0[idx] = num / fmaxf(den, 1e-6f);
            }
            __syncthreads();
            for (int idx = tid; idx < 1080; idx += NTH) {
                int s = idx / 9, f = idx - s * 9;
                float acc = sBO2[f] + S0[s * 9 + f];
                #pragma unroll
                for (int e = 0; e < 9; ++e) acc = fmaf(S0[s * 9 + e], sWO2[f * 9 + e], acc);
                S1[idx] = acc;
            }
            __syncthreads();
            if (tid < 120) {
                int s = tid;
                float sum = 0.f, sq = 0.f;
                #pragma unroll
                for (int f = 0; f < 9; ++f) { float v = S1[s * 9 + f]; sum += v; sq = fmaf(v, v, sq); }
                float mu = sum * (1.f / 9.f);
                float rs = rsqrtf(sq * (1.f / 9.f) - mu * mu + 1e-5f);
                #pragma unroll
                for (int f = 0; f < 9; ++f) {
                    float uo = (S1[s * 9 + f] - mu) * rs * sLN2G[f] + sLN2B[f];
                    sUb[(ss * 9 + f) * 120 + s] = (unsigned short)f2bf(uo);
                }
            }
        }
        __syncthreads();
    }

    // ---- Phase B: lin_attn_4, o == V (R4-proven delete). 240 threads,
    //      1 row/thread, 4 pair-iterations over 7 samples. bf16 u reads
    //      (exact widening); fp32 V/Y with proven summation order.
    for (int i = tid; i < 120; i += NTH) { sBO4[i] = bo4[i]; sLN4G[i] = ln4g[i]; sLN4B[i] = ln4b[i]; }
    for (int p = 0; p < 4; ++p) {
        float* V0 = SCR;               // V[2][1080]
        float* Y0 = SCR + 2160;        // Y[2][1080]
        const int sp = tid / 120, erow = tid - sp * 120;
        const int smp = p * 2 + sp;
        const bool act = (tid < 240) && (smp < SB);
        if (act) {   // V row erow for all 9 vars of sample smp (bf16 u reads)
            const unsigned short* uBb = sUb + smp * 1080;
            float acc[9];
            #pragma unroll
            for (int v = 0; v < 9; ++v) acc[v] = 0.f;
            const float* w0p = &wv4[erow * 120];
            for (int dq = 0; dq < 30; ++dq) {
                float4 wA = *(const float4*)&w0p[dq * 4];
                #pragma unroll
                for (int v = 0; v < 9; ++v) {
                    us4 ub = *(const us4*)&uBb[v * 120 + dq * 4];
                    acc[v] = fmaf(wA.x, bf2f(ub[0]), acc[v]);
                    acc[v] = fmaf(wA.y, bf2f(ub[1]), acc[v]);
                    acc[v] = fmaf(wA.z, bf2f(ub[2]), acc[v]);
                    acc[v] = fmaf(wA.w, bf2f(ub[3]), acc[v]);
                }
            }
            float* dst = V0 + sp * 1080;
            #pragma unroll
            for (int v = 0; v < 9; ++v) dst[v * 120 + erow] = acc[v];
        }
        __syncthreads();
        if (act) {   // Y row erow (wo4 pass + residual; fp32 V, R6 chain)
            const float* vB = V0 + sp * 1080;
            float acc[9];
            #pragma unroll
            for (int v = 0; v < 9; ++v) acc[v] = 0.f;
            const float* w0p = &wo4[erow * 120];
            for (int dq = 0; dq < 30; ++dq) {
                float4 wA = *(const float4*)&w0p[dq * 4];
                #pragma unroll
                for (int v = 0; v < 9; ++v) {
                    float4 u = *(const float4*)&vB[v * 120 + dq * 4];
                    acc[v] = fmaf(wA.x, u.x, acc[v]); acc[v] = fmaf(wA.y, u.y, acc[v]);
                    acc[v] = fmaf(wA.z, u.z, acc[v]); acc[v] = fmaf(wA.w, u.w, acc[v]);
                }
            }
            float* Y = Y0 + sp * 1080;
            #pragma unroll
            for (int v = 0; v < 9; ++v)
                Y[v * 120 + erow] = acc[v] + sBO4[erow] + vB[v * 120 + erow];
        }
        __syncthreads();
        if (tid < 18 && (p * 2 + tid / 9) < SB) {   // LN stats
            int sp2 = tid / 9, v = tid - sp2 * 9;
            const float* Y = Y0 + sp2 * 1080 + v * 120;
            float sum = 0.f, sq = 0.f;
            for (int e = 0; e < 120; ++e) { float t = Y[e]; sum += t; sq = fmaf(t, t, sq); }
            float mu = sum * (1.f / 120.f);
            sMU[tid] = mu;
            sRS[tid] = rsqrtf(sq * (1.f / 120.f) - mu * mu + 1e-5f);
        }
        __syncthreads();
        for (int idx = tid; idx < 540; idx += NTH) {   // LN apply -> bf16 sUb
            int sp2 = idx / 270, off = idx - sp2 * 270;
            int smp2 = p * 2 + sp2;
            int v = off / 30, qq = off - v * 30;
            if (smp2 < SB) {
                const float* Y = Y0 + sp2 * 1080;
                float4 y = *(const float4*)&Y[v * 120 + qq * 4];
                float4 g = *(const float4*)&sLN4G[qq * 4];
                float4 bb = *(const float4*)&sLN4B[qq * 4];
                float mu = sMU[sp2 * 9 + v], rs = sRS[sp2 * 9 + v];
                float ox = (y.x - mu) * rs * g.x + bb.x;
                float oy = (y.y - mu) * rs * g.y + bb.y;
                float oz = (y.z - mu) * rs * g.z + bb.z;
                float ow = (y.w - mu) * rs * g.w + bb.w;
                uint2 pk; pk.x = pk_bf16(ox, oy); pk.y = pk_bf16(oz, ow);
                *(uint2*)&sUb[(smp2 * 9 + v) * 120 + qq * 4] = pk;
            }
        }
        __syncthreads();
    }

    // ---- Phase C: CGLSTM via MFMA — 4 waves x 16 rows, barrier-free steps
    //      (R5/R6-proven: wave-private row stripes + dbuf planes).
    for (int i = tid; i < 2816; i += NTH) sH0[i] = 0.f;   // h0 = 0 (plane 0)
    __syncthreads();

    const int c = lane & 15, q = lane >> 4;
    bf16x8 bfr[8]; float wxv[8], bsv[8];
    int grow[4]; int pcol;
    {
        // Probe 1: A(m,0)=m, B(0,n)=1  -> D slot value = its ROW
        // Probe 2: A(m,0)=1, B(0,n)=n  -> D slot value = its COLUMN
        bf16x8 pa, pb, pa2, pb2;
        #pragma unroll
        for (int j = 0; j < 8; ++j) { pa[j] = 0; pb[j] = 0; pa2[j] = 0; pb2[j] = 0; }
        if (q == 0) {
            pa[0]  = f2bf((float)c); pb[0]  = f2bf(1.0f);
            pa2[0] = f2bf(1.0f);     pb2[0] = f2bf((float)c);
        }
        f32x4 zc; zc[0] = zc[1] = zc[2] = zc[3] = 0.f;
        f32x4 prr = __builtin_amdgcn_mfma_f32_16x16x32_bf16(pa,  pb,  zc, 0, 0, 0);
        f32x4 pcc = __builtin_amdgcn_mfma_f32_16x16x32_bf16(pa2, pb2, zc, 0, 0, 0);
        #pragma unroll
        for (int r = 0; r < 4; ++r) grow[r] = wv * 16 + (int)(prr[r] + 0.5f);
        pcol = (int)(pcc[0] + 0.5f);

        #pragma unroll
        for (int T = 0; T < 8; ++T) {
            int gate = T >> 1, kk = ((T & 1) << 4) + pcol;
            const float* wr; float wx, bs;
            if (gate < 3) {
                int n = gate * 32 + kk;
                wr = &w_hh[n * 32]; wx = w_ih[n]; bs = b_ih[n] + b_hh[n];
            } else {
                wr = &cg_uw[kk * 32]; wx = cg_w[kk]; bs = cg_ub[kk];
            }
            bf16x8 tv;
            #pragma unroll
            for (int j = 0; j < 8; ++j) tv[j] = f2bf(wr[q * 8 + j]);
            bfr[T] = tv; wxv[T] = wx; bsv[T] = bs;
        }
    }
    float cst[8];
    #pragma unroll
    for (int i = 0; i < 8; ++i) cst[i] = 0.f;
    const int live9 = nsamp * 9;
    const float* ar0 = &sH0[(wv * 16 + c) * 44 + q * 8];
    const float* ar1 = &sH1[(wv * 16 + c) * 44 + q * 8];

// One LSTM step, no barrier: read plane RP, write plane WPL (disjoint).
#define LSTM_STEP(RP, WPL, XARR)                                               \
    {                                                                          \
        float4 hA = *(const float4*)(RP);                                      \
        float4 hB = *(const float4*)((RP) + 4);                                \
        union { unsigned u[4]; bf16x8 v; } afu;                                \
        afu.u[0] = pk_bf16(hA.x, hA.y);                                        \
        afu.u[1] = pk_bf16(hA.z, hA.w);                                        \
        afu.u[2] = pk_bf16(hB.x, hB.y);                                        \
        afu.u[3] = pk_bf16(hB.z, hB.w);                                        \
        f32x4 acc[8];                                                          \
        _Pragma("unroll")                                                      \
        for (int T = 0; T < 8; ++T) {                                          \
            f32x4 ci;                                                          \
            _Pragma("unroll")                                                  \
            for (int r = 0; r < 4; ++r) ci[r] = fmaf(wxv[T], XARR[r], bsv[T]); \
            acc[T] = __builtin_amdgcn_mfma_f32_16x16x32_bf16(afu.v, bfr[T], ci, 0, 0, 0); \
        }                                                                      \
        _Pragma("unroll")                                                      \
        for (int kh = 0; kh < 2; ++kh) {                                       \
            _Pragma("unroll")                                                  \
            for (int r = 0; r < 4; ++r) {                                      \
                float si  = fast_sigmoid(acc[kh][r]);                          \
                float sf  = fast_sigmoid(acc[2 + kh][r]);                      \
                float tg  = fast_tanh(acc[4 + kh][r]);                         \
                float sgc = fast_sigmoid(acc[6 + kh][r]);                      \
                float cn = fmaf(sf, cst[kh * 4 + r], si * tg);                 \
                cst[kh * 4 + r] = cn;                                          \
                (WPL)[grow[r] * 44 + (kh << 4) + pcol] = sgc * fast_tanh(cn);  \
            }                                                                  \
        }                                                                      \
    }

    for (int t = 0; t < 120; t += 2) {
        float xa[4], xb[4];
        #pragma unroll
        for (int r = 0; r < 4; ++r) {
            if (grow[r] < live9) {
                us2 xv = *(const us2*)&sUb[grow[r] * 120 + t];
                xa[r] = bf2f(xv[0]); xb[r] = bf2f(xv[1]);
            } else { xa[r] = 0.f; xb[r] = 0.f; }
        }
        LSTM_STEP(ar0, sH1, xa)     // even step: plane0 -> plane1
        LSTM_STEP(ar1, sH0, xb)     // odd step:  plane1 -> plane0
    }
    __syncthreads();   // publish final h (plane 0) to all waves

    // cglstm_out (output 0) straight from the LDS h-plane
    for (int idx = tid; idx < SB * 288; idx += NTH) {
        int ssd = idx / 288, r = idx - ssd * 288;
        if (ssd < nsamp) {
            int v = r >> 5, k = r & 31;
            out[(size_t)(b0 + ssd) * 288 + r] = sH0[(ssd * 9 + v) * 44 + k];
        }
    }

    // ---- Phase D: conv6(softplus) -> conv7(tanh) -> RevIN ----
    // sT1 aliases the dead sUb region (fp32 3780); sTF/sST alias dead sH1.
    for (int idx = tid; idx < SB * 540; idx += NTH) {
        int ssd = idx / 540, rem = idx - ssd * 540;
        int v = rem / 60, j = rem - v * 60;
        if (ssd < nsamp) {
            float acc = b6[j];
            const float4* wr4 = (const float4*)&w6[j * 32];
            const float4* hv = (const float4*)&sH0[(ssd * 9 + v) * 44];
            #pragma unroll
            for (int qq = 0; qq < 8; ++qq) {
                float4 w = wr4[qq], h = hv[qq];
                acc = fmaf(w.x, h.x, acc); acc = fmaf(w.y, h.y, acc);
                acc = fmaf(w.z, h.z, acc); acc = fmaf(w.w, h.w, acc);
            }
            sT1[idx] = acc > 15.f ? acc : log1pf(__expf(acc));
        }
    }
    __syncthreads();
    for (int idx = tid; idx < SB * 135; idx += NTH) {
        int ssd = idx / 135, rem = idx - ssd * 135;
        int v = rem / 15, f = rem - v * 15;
        if (ssd < nsamp) {
            float acc = b7[f];
            const float4* wr = (const float4*)&w7[f * 60];
            const float4* tv = (const float4*)&sT1[ssd * 540 + v * 60];
            #pragma unroll
            for (int qq = 0; qq < 15; ++qq) {
                float4 w = wr[qq], h = tv[qq];
                acc = fmaf(w.x, h.x, acc); acc = fmaf(w.y, h.y, acc);
                acc = fmaf(w.z, h.z, acc); acc = fmaf(w.w, h.w, acc);
            }
            sTF[idx] = fast_tanh(acc);
        }
    }
    __syncthreads();
    if (tid < SB && tid < nsamp) {
        const float* tf = &sTF[tid * 135];
        float sum = 0.f;
        for (int i = 0; i < 135; ++i) sum += tf[i];
        float mu = sum * (1.f / 135.f);
        float sq = 0.f;
        for (int i = 0; i < 135; ++i) { float d = tf[i] - mu; sq = fmaf(d, d, sq); }
        float sd = sqrtf(sq * (1.f / 134.f));  // ddof=1
        sST[tid * 2]     = mu;
        sST[tid * 2 + 1] = 1.f / fmaxf(sd, 1e-5f);
    }
    __syncthreads();
    const size_t encbase = (size_t)Bn * 288;
    for (int idx = tid; idx < SB * 135; idx += NTH) {
        int ssd = idx / 135, j = idx - ssd * 135;
        if (ssd < nsamp) {
            int qq = j / 15, pp = j - qq * 15;
            float val = (sTF[ssd * 135 + pp * 9 + qq] - sST[ssd * 2]) * sST[ssd * 2 + 1] * rev_w[j] + rev_b[j];
            out[encbase + (size_t)(b0 + ssd) * 135 + j] = val;
        }
    }
}

extern "C" void kernel_launch(void* const* d_in, const int* in_sizes, int n_in,
                              void* d_out, int out_size, void* d_ws, size_t ws_size,
                              hipStream_t stream) {
    const float* x    = (const float*)d_in[0];
    const float* bn_g = (const float*)d_in[1];
    const float* bn_b = (const float*)d_in[2];
    const float* bn_m = (const float*)d_in[3];
    const float* bn_v = (const float*)d_in[4];
    const float* wq2  = (const float*)d_in[5];
    const float* wk2  = (const float*)d_in[6];
    const float* wv2  = (const float*)d_in[7];
    const float* wo2  = (const float*)d_in[8];
    const float* bo2  = (const float*)d_in[9];
    const float* ln2g = (const float*)d_in[10];
    const float* ln2b = (const float*)d_in[11];
    const float* wq4  = (const float*)d_in[12];
    const float* wk4  = (const float*)d_in[13];
    const float* wv4  = (const float*)d_in[14];
    const float* wo4  = (const float*)d_in[15];
    const float* bo4  = (const float*)d_in[16];
    const float* ln4g = (const float*)d_in[17];
    const float* ln4b = (const float*)d_in[18];
    const float* w_ih = (const float*)d_in[19];
    const float* w_hh = (const float*)d_in[20];
    const float* b_ih = (const float*)d_in[21];
    const float* b_hh = (const float*)d_in[22];
    const float* cg_w = (const float*)d_in[23];
    const float* cg_uw= (const float*)d_in[24];
    const float* cg_ub= (const float*)d_in[25];
    const float* w6   = (const float*)d_in[26];
    const float* b6   = (const float*)d_in[27];
    const float* w7   = (const float*)d_in[28];
    const float* b7   = (const float*)d_in[29];
    const float* rev_w= (const float*)d_in[30];
    const float* rev_b= (const float*)d_in[31];

    int Bn = in_sizes[0] / 1080;
    int grid = (Bn + SB - 1) / SB;
    hipLaunchKernelGGL(se_kernel, dim3(grid), dim3(NTH), 0, stream,
                       x, bn_g, bn_b, bn_m, bn_v, wq2, wk2, wv2, wo2, bo2, ln2g, ln2b,
                       wq4, wk4, wv4, wo4, bo4, ln4g, ln4b,
                       w_ih, w_hh, b_ih, b_hh, cg_w, cg_uw, cg_ub,
                       w6, b6, w7, b7, rev_w, rev_b,
                       (float*)d_out, Bn);
}